// Round 7
// baseline (225.581 us; speedup 1.0000x reference)
//
#include <hip/hip_runtime.h>
#include <hip/hip_bf16.h>

#define Dd 2048
#define Ss 2048
#define Bb 2
#define Hh 16
#define HDd 128
#define BSs (Bb*Ss)
#define NTIL 32  // 2048 / 64 K-tiles

typedef __bf16 bf16;
typedef __bf16 bf16x8 __attribute__((ext_vector_type(8)));
typedef __bf16 bf16x4 __attribute__((ext_vector_type(4)));
typedef float f32x4 __attribute__((ext_vector_type(4)));

__device__ __forceinline__ void gload_lds16(const void* g, void* l) {
  __builtin_amdgcn_global_load_lds((__attribute__((address_space(1))) void*)(g),
                                   (__attribute__((address_space(3))) void*)(l), 16, 0, 0);
}

template <int N>
__device__ __forceinline__ void waitv() {
  if constexpr (N == 0) asm volatile("s_waitcnt vmcnt(0)" ::: "memory");
  else if constexpr (N == 6) asm volatile("s_waitcnt vmcnt(6)" ::: "memory");
  // N < 0: no wait
}

// ---------------- x -> bf16 ----------------
__global__ void k_cvtx(const float* __restrict__ x, bf16* __restrict__ xb) {
  int i = (blockIdx.x * 256 + threadIdx.x) * 4;
  f32x4 v = *(const f32x4*)(x + i);
  bf16x4 o;
  o[0] = (bf16)v[0]; o[1] = (bf16)v[1]; o[2] = (bf16)v[2]; o[3] = (bf16)v[3];
  *(bf16x4*)(xb + i) = o;
}

// ------------- W [K][N] fp32 -> transposed bf16 -------------
// Wq/Wk/Wv -> wqkvt HEAD-INTERLEAVED rows: feature f of matrix z ->
// row (f>>7)*384 + z*128 + (f&127); so n-slab i of 384 = head i's (Q,K,V) triple.
// Wo -> wot flat [N][K].
__global__ void k_tw(const float* __restrict__ Wq, const float* __restrict__ Wk,
                     const float* __restrict__ Wv, const float* __restrict__ Wo,
                     bf16* __restrict__ wqkvt, bf16* __restrict__ wot) {
  int zz = blockIdx.z;
  const float* W = (zz == 0) ? Wq : (zz == 1) ? Wk : (zz == 2) ? Wv : Wo;
  bf16* T = (zz < 3) ? wqkvt : wot;
  __shared__ float t[64][65];
  int n0 = blockIdx.x * 64, k0 = blockIdx.y * 64;
  // 64-col block never crosses a 128-feature head boundary (n0 % 128 in {0,64})
  int trow0 = (zz < 3) ? ((n0 >> 7) * 384 + zz * 128 + (n0 & 127)) : n0;
  int tid = threadIdx.x;  // 256
#pragma unroll
  for (int rr = 0; rr < 4; rr++) {
    int r = (tid >> 4) + rr * 16;
    f32x4 vv = *(const f32x4*)(W + (size_t)(k0 + r) * Dd + n0 + (tid & 15) * 4);
#pragma unroll
    for (int j = 0; j < 4; j++) t[r][(tid & 15) * 4 + j] = vv[j];
  }
  __syncthreads();
#pragma unroll
  for (int rr = 0; rr < 4; rr++) {
    int n = rr * 16 + (tid >> 4);
    int kb = (tid & 15) * 4;
    bf16x4 o;
#pragma unroll
    for (int j = 0; j < 4; j++) o[j] = (bf16)t[kb + j][n];
    *(bf16x4*)(T + (size_t)(trow0 + n) * Dd + k0 + kb) = o;
  }
}

// ------------- doc position ids (prefix-max scan per batch) -------------
__global__ void k_pos(const int* __restrict__ doc, int* __restrict__ pos) {
  int b = blockIdx.x;
  __shared__ int bp[2][Ss];
  const int* db = doc + (size_t)b * Ss;
  for (int i = threadIdx.x; i < Ss; i += 1024) {
    int bd = (i == 0) || (db[i] != db[i - 1]);
    bp[0][i] = bd ? i : 0;
  }
  __syncthreads();
  int src = 0;
  for (int off = 1; off < Ss; off <<= 1) {
    for (int i = threadIdx.x; i < Ss; i += 1024) {
      int v = bp[src][i];
      if (i >= off) v = max(v, bp[src][i - off]);
      bp[1 - src][i] = v;
    }
    __syncthreads();
    src = 1 - src;
  }
  for (int i = threadIdx.x; i < Ss; i += 1024)
    pos[(size_t)b * Ss + i] = i - bp[src][i];
}

// ================= 256x384 BK=64 GEMM core for QKV (double-buffered, dist-1) =================
// A [M][2048] bf16, B = head-interleaved wqkvt. Tile 256x384, 8 waves 2(M) x 4(N),
// wave tile 128x96 (acc[8][6]). K-tile 64 (128-B rows, swizzle cb ^= (row&7)<<4,
// inverse-applied on global source; gload_lds dest linear).
// LDS: 2 buf x (A 32 KB + B 48 KB) = 160 KiB (full pool). 10 loads/thread/tile.
// Per K-tile t: issue 10 loads for t+1 -> {kk=0,1: read bf[6]; {mh=0,1: read af[4];
// 24 MFMA}} -> vmcnt(0) (gap = full ~3000-cyc tile) -> s_barrier.
// Long per-tile compute makes distance-1 equivalent to the old distance-2 in cycles.
__device__ __forceinline__ void stage384(const char* gA, const char* gB,
                                         int m0, int n0, int t, int buf,
                                         char* AL, char* BL, int tid) {
  int ktb = t * 128;
#pragma unroll
  for (int p = 0; p < 4; p++) {
    int o = p * 8192 + tid * 16;
    int r = o >> 7, cb = o & 127;
    gload_lds16(gA + (size_t)(m0 + r) * 4096 + ktb + (cb ^ ((r & 7) << 4)),
                AL + buf * 32768 + o);
  }
#pragma unroll
  for (int p = 0; p < 6; p++) {
    int o = p * 8192 + tid * 16;
    int r = o >> 7, cb = o & 127;
    gload_lds16(gB + (size_t)(n0 + r) * 4096 + ktb + (cb ^ ((r & 7) << 4)),
                BL + buf * 49152 + o);
  }
}

template <bool STAGE, int WV>
__device__ __forceinline__ void do_tile384(const char* gA, const char* gB, int m0, int n0,
                                           int t, int bi, char* AL, char* BL, int tid,
                                           int wr, int wc, int ln, int g,
                                           f32x4 (&acc)[8][6]) {
  if (STAGE) stage384(gA, gB, m0, n0, t + 1, bi ^ 1, AL, BL, tid);
  const char* tA = AL + bi * 32768;
  const char* tB = BL + bi * 49152;
#pragma unroll
  for (int kk = 0; kk < 2; kk++) {
    bf16x8 bf[6];
#pragma unroll
    for (int nq = 0; nq < 6; nq++) {
      int row = wc * 96 + nq * 16 + ln;
      bf[nq] = *(const bf16x8*)(tB + row * 128 + ((kk * 64 + g * 16) ^ ((row & 7) << 4)));
    }
#pragma unroll
    for (int mh = 0; mh < 2; mh++) {
      bf16x8 af[4];
#pragma unroll
      for (int mq = 0; mq < 4; mq++) {
        int row = wr * 128 + mh * 64 + mq * 16 + ln;
        af[mq] = *(const bf16x8*)(tA + row * 128 + ((kk * 64 + g * 16) ^ ((row & 7) << 4)));
      }
      __builtin_amdgcn_s_setprio(1);
#pragma unroll
      for (int mq = 0; mq < 4; mq++)
#pragma unroll
        for (int nq = 0; nq < 6; nq++)
          acc[mh * 4 + mq][nq] =
              __builtin_amdgcn_mfma_f32_16x16x32_bf16(af[mq], bf[nq], acc[mh * 4 + mq][nq], 0, 0, 0);
      __builtin_amdgcn_s_setprio(0);
    }
  }
  waitv<WV>();
  if (WV >= 0) __builtin_amdgcn_s_barrier();
}

// ------------- fused QKV projection + RoPE epilogue (256x384 tiles, 256 blocks = 1 exact round) -------------
// n-slab nt = head nt. Cols [0,128)=Q, [128,256)=K (RoPE via LDS-transpose, 4 passes
// of 64 rows), [256,384)=V (direct transposed store [B][H][HD][S]).
// XCD-partitioned: XCD x owns heads {2x, 2x+1} (B 3 MB, L2-resident), mt-major.
__global__ __launch_bounds__(512, 2) void k_qkv384(const bf16* __restrict__ xb,
                                                   const bf16* __restrict__ wqkvt,
                                                   const int* __restrict__ pos,
                                                   bf16* __restrict__ q,
                                                   bf16* __restrict__ k,
                                                   bf16* __restrict__ vt) {
  __shared__ char SLM[163840];  // GEMM: A 2x32K + B 2x48K = 160K; epilogue: 64x260 f32 (65 KB)
  char* AL = SLM;
  char* BL = SLM + 65536;
  int bid = blockIdx.x;                    // 256 blocks
  int x = bid & 7, j = bid >> 3;           // x = XCD, j = 0..31
  int nt = x * 2 + (j >> 4);               // 2 heads per XCD
  int mt = j & 15;                         // mt-major within each head-panel
  int m0 = mt * 256, n0 = nt * 384;

  const int tid = threadIdx.x;
  const int l = tid & 63, w = tid >> 6;
  const int wr = w >> 2, wc = w & 3;
  const int g = l >> 4, ln = l & 15;

  f32x4 acc[8][6];
  f32x4 z = {0.f, 0.f, 0.f, 0.f};
#pragma unroll
  for (int i = 0; i < 8; i++)
#pragma unroll
    for (int n = 0; n < 6; n++) acc[i][n] = z;

  const char* gA = (const char*)xb;
  const char* gB = (const char*)wqkvt;
  stage384(gA, gB, m0, n0, 0, 0, AL, BL, tid);
  waitv<0>();
  __builtin_amdgcn_s_barrier();
  for (int t = 0; t < NTIL - 1; t++)
    do_tile384<true, 0>(gA, gB, m0, n0, t, t & 1, AL, BL, tid, wr, wc, ln, g, acc);
  do_tile384<false, -1>(gA, gB, m0, n0, NTIL - 1, (NTIL - 1) & 1, AL, BL, tid, wr, wc, ln, g, acc);

  int h = nt;                               // head index
  int bix = m0 >> 11;
  int sl0 = m0 & 2047;                      // 256-row tile never crosses batch boundary

  // ---- V frags (cols >= 256): direct transposed store [B][H][HD][S], 8 B stores ----
#pragma unroll
  for (int mq = 0; mq < 8; mq++) {
    int sl = sl0 + wr * 128 + mq * 16 + g * 4;
#pragma unroll
    for (int nq = 0; nq < 6; nq++) {
      int cb0 = wc * 96 + nq * 16;
      if (cb0 >= 256) {
        int hd = cb0 - 256 + ln;
        bf16x4 o;
#pragma unroll
        for (int r2 = 0; r2 < 4; r2++) o[r2] = (bf16)acc[mq][nq][r2];
        *(bf16x4*)(vt + (((size_t)(bix * Hh + h) * HDd + hd) * Ss + sl)) = o;
      }
    }
  }

  // ---- Q/K frags (cols < 256): LDS-transpose, in-register RoPE, 16 B stores ----
  float* T = (float*)SLM;                   // 64 rows x stride 260 f32 per pass
  const float c1 = 0.14391156642398168f;    // ln(10000)/64
  int cg = (tid & 31) * 8;                  // 8 consecutive cols in [0,256)
  int zz = cg >> 7;                         // 0=Q 1=K (uniform per thread)
  int hd0 = cg & 127;
  bf16* dst = (zz == 0) ? q : k;
  float fr[4];
#pragma unroll
  for (int pr = 0; pr < 4; pr++)
    fr[pr] = __expf(-(float)((hd0 >> 1) + pr) * c1);

#pragma unroll
  for (int pass = 0; pass < 4; pass++) {
    __syncthreads();
    // scatter 64 rows: owned by waves with wr == pass>>1, frags mq in [(pass&1)*4, +4)
    if (wr == (pass >> 1)) {
#pragma unroll
      for (int mq2 = 0; mq2 < 4; mq2++) {
        int mq = (pass & 1) * 4 + mq2;
#pragma unroll
        for (int nq = 0; nq < 6; nq++) {
          int cb0 = wc * 96 + nq * 16;
          if (cb0 < 256) {
            int rb = mq2 * 16 + g * 4;
#pragma unroll
            for (int r2 = 0; r2 < 4; r2++)
              T[(rb + r2) * 260 + cb0 + ln] = acc[mq][nq][r2];
          }
        }
      }
    }
    __syncthreads();
#pragma unroll
    for (int j2 = 0; j2 < 4; j2++) {
      int r = j2 * 16 + (tid >> 5);
      int sg = m0 + pass * 64 + r;
      float p = (float)pos[sg];
      f32x4 v0 = *(const f32x4*)(T + r * 260 + cg);
      f32x4 v1 = *(const f32x4*)(T + r * 260 + cg + 4);
      float e0[4] = {v0[0], v0[2], v1[0], v1[2]};
      float e1[4] = {v0[1], v0[3], v1[1], v1[3]};
      int s = sg & 2047;
      bf16x8 o;
#pragma unroll
      for (int pr = 0; pr < 4; pr++) {
        float ang = p * fr[pr];
        float sn, cs;
        __sincosf(ang, &sn, &cs);
        o[2 * pr]     = (bf16)(e0[pr] * cs - e1[pr] * sn);
        o[2 * pr + 1] = (bf16)(e1[pr] * cs + e0[pr] * sn);
      }
      *(bf16x8*)(dst + (((size_t)(bix * Hh + h) * Ss + s) * HDd + hd0)) = o;
    }
  }
}

// ================= 128x256 BK=64 core (round-6, unchanged) for the out-projection =================
__device__ __forceinline__ void stage64(const char* gA, const char* gB,
                                        int m0, int n0, int t, int buf,
                                        char* AL, char* BL, int tid) {
  int ktb = t * 128;  // K-tile byte offset in a 4096 B row
#pragma unroll
  for (int p = 0; p < 2; p++) {
    int o = p * 8192 + tid * 16;
    int r = o >> 7, cb = o & 127;
    gload_lds16(gA + (size_t)(m0 + r) * 4096 + ktb + (cb ^ ((r & 7) << 4)),
                AL + buf * 16384 + o);
  }
#pragma unroll
  for (int p = 0; p < 4; p++) {
    int o = p * 8192 + tid * 16;
    int r = o >> 7, cb = o & 127;
    gload_lds16(gB + (size_t)(n0 + r) * 4096 + ktb + (cb ^ ((r & 7) << 4)),
                BL + buf * 32768 + o);
  }
}

template <bool STAGE, int WV>
__device__ __forceinline__ void do_tile64(const char* gA, const char* gB, int m0, int n0,
                                          int t, int bi, int b2, char* AL, char* BL, int tid,
                                          int wr, int wc, int ln, int g,
                                          f32x4 (&acc)[4][4]) {
  if (STAGE) stage64(gA, gB, m0, n0, t + 2, b2, AL, BL, tid);
  const char* tA = AL + bi * 16384;
  const char* tB = BL + bi * 32768;
#pragma unroll
  for (int kk = 0; kk < 2; kk++) {
    bf16x8 af[4], bf[4];
#pragma unroll
    for (int mq = 0; mq < 4; mq++) {
      int row = wr * 64 + mq * 16 + ln;
      af[mq] = *(const bf16x8*)(tA + row * 128 + ((kk * 64 + g * 16) ^ ((row & 7) << 4)));
    }
#pragma unroll
    for (int nq = 0; nq < 4; nq++) {
      int row = wc * 64 + nq * 16 + ln;
      bf[nq] = *(const bf16x8*)(tB + row * 128 + ((kk * 64 + g * 16) ^ ((row & 7) << 4)));
    }
    __builtin_amdgcn_s_setprio(1);
#pragma unroll
    for (int mq = 0; mq < 4; mq++)
#pragma unroll
      for (int nq = 0; nq < 4; nq++)
        acc[mq][nq] = __builtin_amdgcn_mfma_f32_16x16x32_bf16(af[mq], bf[nq], acc[mq][nq], 0, 0, 0);
    __builtin_amdgcn_s_setprio(0);
  }
  waitv<WV>();
  __builtin_amdgcn_s_barrier();
}

__device__ __forceinline__ void gemm64_core(const bf16* gA_, const bf16* gB_,
                                            int m0, int n0, char* AL, char* BL,
                                            f32x4 (&acc)[4][4]) {
  const char* gA = (const char*)gA_;
  const char* gB = (const char*)gB_;
  const int tid = threadIdx.x;
  const int l = tid & 63, w = tid >> 6;
  const int wr = w >> 2, wc = w & 3;
  const int g = l >> 4, ln = l & 15;
  f32x4 z = {0.f, 0.f, 0.f, 0.f};
#pragma unroll
  for (int i = 0; i < 4; i++)
#pragma unroll
    for (int n = 0; n < 4; n++) acc[i][n] = z;

  stage64(gA, gB, m0, n0, 0, 0, AL, BL, tid);
  stage64(gA, gB, m0, n0, 1, 1, AL, BL, tid);
  waitv<6>();
  __builtin_amdgcn_s_barrier();

  for (int tt = 0; tt < 10; tt++) {
    int t = tt * 3;
    do_tile64<true, 6>(gA, gB, m0, n0, t,     0, 2, AL, BL, tid, wr, wc, ln, g, acc);
    do_tile64<true, 6>(gA, gB, m0, n0, t + 1, 1, 0, AL, BL, tid, wr, wc, ln, g, acc);
    do_tile64<true, 6>(gA, gB, m0, n0, t + 2, 2, 1, AL, BL, tid, wr, wc, ln, g, acc);
  }
  do_tile64<false, 0>(gA, gB, m0, n0, 30, 0, 0, AL, BL, tid, wr, wc, ln, g, acc);
  do_tile64<false, -1>(gA, gB, m0, n0, 31, 1, 0, AL, BL, tid, wr, wc, ln, g, acc);
}

// ------------- final projection + bias (fp32 out), 128x256 tiles, 256 blocks = 1 exact round -------------
// XCD-partitioned: XCD x owns nt = x (one 0.5 MB wot panel, L2-resident) x all 32 mt.
__global__ __launch_bounds__(512, 2) void k_out256(const bf16* __restrict__ ctx,
                                                   const bf16* __restrict__ wot,
                                                   const float* __restrict__ bo,
                                                   float* __restrict__ outp) {
  __shared__ char AL[49152];
  __shared__ char BL[98304];
  int bid = blockIdx.x;                    // 256 blocks
  int x = bid & 7, j = bid >> 3;           // x = XCD, j = 0..31
  int mt = j, nt = x;
  int m0 = mt * 128, n0 = nt * 256;

  f32x4 acc[4][4];
  gemm64_core(ctx, wot, m0, n0, AL, BL, acc);

  const int l = threadIdx.x & 63, w = threadIdx.x >> 6;
  const int wr = w >> 2, wc = w & 3, g = l >> 4, ln = l & 15;
  float bov[4];
#pragma unroll
  for (int nq = 0; nq < 4; nq++)
    bov[nq] = bo[n0 + wc * 64 + nq * 16 + ln];
#pragma unroll
  for (int mq = 0; mq < 4; mq++)
#pragma unroll
    for (int r2 = 0; r2 < 4; r2++) {
      int row = m0 + wr * 64 + mq * 16 + g * 4 + r2;
#pragma unroll
      for (int nq = 0; nq < 4; nq++) {
        int col = n0 + wc * 64 + nq * 16 + ln;
        outp[(size_t)row * Dd + col] = acc[mq][nq][r2] + bov[nq];
      }
    }
}

// ------------- flash attention with doc+causal mask (round-6, unchanged) -------------
__global__ __launch_bounds__(256) void k_attn(const bf16* __restrict__ q,
                                              const bf16* __restrict__ k,
                                              const bf16* __restrict__ vt,
                                              const int* __restrict__ pos,
                                              bf16* __restrict__ ctx) {
  __shared__ bf16 Ks[64 * 128];    // K tile  [kv][hd]
  __shared__ bf16 Vts[128 * 64];   // Vt tile [hd][kv]
  __shared__ bf16 Pw[4][16 * 64];  // per-wave P [qrow][kv]
  int bid = blockIdx.x;            // 1024
  int xc = bid & 7, jj = bid >> 3; // jj = 0..127
  int bh = xc * 4 + (jj >> 5);     // 4 heads per XCD
  int qt = jj & 31;
  int b = bh >> 4, h = bh & 15;
  int q0 = qt * 64;
  const int tid = threadIdx.x, l = tid & 63, w = tid >> 6, g = l >> 4, ln = l & 15;
  const bf16* qb = q + (size_t)bh * Ss * HDd;
  const bf16* kb = k + (size_t)bh * Ss * HDd;
  const bf16* vb = vt + (size_t)bh * Ss * HDd;

  bf16x8 qf[4];
  int qr = q0 + w * 16 + ln;
#pragma unroll
  for (int ks = 0; ks < 4; ks++)
    qf[ks] = *(const bf16x8*)(qb + (size_t)qr * HDd + ks * 32 + 8 * g);

  int rrow[4], dstart[4];
  float m[4], lsum[4];
#pragma unroll
  for (int r2 = 0; r2 < 4; r2++) {
    rrow[r2] = q0 + w * 16 + 4 * g + r2;
    dstart[r2] = rrow[r2] - pos[(size_t)b * Ss + rrow[r2]];
    m[r2] = -1e30f;
    lsum[r2] = 0.f;
  }
  f32x4 oacc[8];
  f32x4 z = {0.f, 0.f, 0.f, 0.f};
#pragma unroll
  for (int n = 0; n < 8; n++) oacc[n] = z;

  int kt_start = (q0 - pos[(size_t)b * Ss + q0]) >> 6;
  const float iscale = 0.08838834764831845f;  // 1/sqrt(128)

  for (int kt = kt_start; kt <= qt; kt++) {
    int kv0 = kt * 64;
#pragma unroll
    for (int i2 = 0; i2 < 4; i2++) {
      int o = i2 * 4096 + w * 1024 + l * 16;
      int rk = o >> 8, cbk = o & 255;
      gload_lds16((const char*)kb + (size_t)(kv0 + rk) * 256 + cbk,
                  (char*)Ks + i2 * 4096 + w * 1024);
      int rv = o >> 7, cbv = o & 127;
      gload_lds16((const char*)vb + (size_t)rv * (Ss * 2) + (size_t)kv0 * 2 + cbv,
                  (char*)Vts + i2 * 4096 + w * 1024);
    }
    __syncthreads();

    f32x4 sc[4];
#pragma unroll
    for (int n = 0; n < 4; n++) {
      f32x4 a = z;
#pragma unroll
      for (int ks = 0; ks < 4; ks++) {
        bf16x8 bfrag = *(const bf16x8*)(Ks + (n * 16 + ln) * 128 + ks * 32 + 8 * g);
        a = __builtin_amdgcn_mfma_f32_16x16x32_bf16(qf[ks], bfrag, a, 0, 0, 0);
      }
      sc[n] = a;
    }

    float pmax[4] = {-1e30f, -1e30f, -1e30f, -1e30f};
    float pv[4][4];
#pragma unroll
    for (int n = 0; n < 4; n++) {
      int kvc = kv0 + n * 16 + ln;
#pragma unroll
      for (int r2 = 0; r2 < 4; r2++) {
        bool ok = (kvc <= rrow[r2]) && (kvc >= dstart[r2]);
        float sv = ok ? sc[n][r2] * iscale : -1e30f;
        pv[n][r2] = sv;
        pmax[r2] = fmaxf(pmax[r2], sv);
      }
    }
#pragma unroll
    for (int off = 1; off < 16; off <<= 1)
#pragma unroll
      for (int r2 = 0; r2 < 4; r2++)
        pmax[r2] = fmaxf(pmax[r2], __shfl_xor(pmax[r2], off, 64));

    float alpha[4];
#pragma unroll
    for (int r2 = 0; r2 < 4; r2++) {
      float mn = fmaxf(m[r2], pmax[r2]);
      alpha[r2] = __expf(m[r2] - mn);
      m[r2] = mn;
    }

    float rs[4] = {0.f, 0.f, 0.f, 0.f};
#pragma unroll
    for (int n = 0; n < 4; n++) {
      int kvc = kv0 + n * 16 + ln;
#pragma unroll
      for (int r2 = 0; r2 < 4; r2++) {
        bool ok = (kvc <= rrow[r2]) && (kvc >= dstart[r2]);
        float p = ok ? __expf(pv[n][r2] - m[r2]) : 0.f;
        rs[r2] += p;
        Pw[w][(4 * g + r2) * 64 + n * 16 + ln] = (bf16)p;
      }
    }
#pragma unroll
    for (int off = 1; off < 16; off <<= 1)
#pragma unroll
      for (int r2 = 0; r2 < 4; r2++) rs[r2] += __shfl_xor(rs[r2], off, 64);
#pragma unroll
    for (int r2 = 0; r2 < 4; r2++) lsum[r2] = lsum[r2] * alpha[r2] + rs[r2];
#pragma unroll
    for (int n = 0; n < 8; n++)
#pragma unroll
      for (int r2 = 0; r2 < 4; r2++) oacc[n][r2] *= alpha[r2];
    __syncthreads();

#pragma unroll
    for (int n = 0; n < 8; n++) {
#pragma unroll
      for (int ks = 0; ks < 2; ks++) {
        bf16x8 pa = *(const bf16x8*)(&Pw[w][ln * 64 + ks * 32 + 8 * g]);
        bf16x8 vfr = *(const bf16x8*)(Vts + (n * 16 + ln) * 64 + ks * 32 + 8 * g);
        oacc[n] = __builtin_amdgcn_mfma_f32_16x16x32_bf16(pa, vfr, oacc[n], 0, 0, 0);
      }
    }
    __syncthreads();
  }

#pragma unroll
  for (int n = 0; n < 8; n++)
#pragma unroll
    for (int r2 = 0; r2 < 4; r2++) {
      float val = oacc[n][r2] / lsum[r2];
      ctx[((size_t)(b * Ss + rrow[r2])) * Dd + h * HDd + n * 16 + ln] = (bf16)val;
    }
}

extern "C" void kernel_launch(void* const* d_in, const int* in_sizes, int n_in,
                              void* d_out, int out_size, void* d_ws, size_t ws_size,
                              hipStream_t stream) {
  const float* x = (const float*)d_in[0];
  const int* doc = (const int*)d_in[1];
  const float* Wq = (const float*)d_in[2];
  const float* Wk = (const float*)d_in[3];
  const float* Wv = (const float*)d_in[4];
  const float* Wo = (const float*)d_in[5];
  const float* bo = (const float*)d_in[6];
  float* outp = (float*)d_out;

  char* ws = (char*)d_ws;
  size_t off = 0;
  auto alloc = [&](size_t bytes) {
    char* p = ws + off;
    off += (bytes + 255) & ~(size_t)255;
    return p;
  };
  bf16* xb = (bf16*)alloc((size_t)BSs * Dd * 2);
  bf16* wqkvt = (bf16*)alloc((size_t)3 * Dd * Dd * 2);  // head-interleaved [6144][2048]
  bf16* wot = (bf16*)alloc((size_t)Dd * Dd * 2);
  bf16* qd = (bf16*)alloc((size_t)BSs * Dd * 2);
  bf16* kd = (bf16*)alloc((size_t)BSs * Dd * 2);
  bf16* vtd = (bf16*)alloc((size_t)BSs * Dd * 2);  // V stored transposed directly
  bf16* ctxd = (bf16*)alloc((size_t)BSs * Dd * 2);
  int* pos = (int*)alloc((size_t)BSs * 4);

  k_cvtx<<<(BSs * Dd) / 1024, 256, 0, stream>>>(x, xb);
  k_tw<<<dim3(Dd / 64, Dd / 64, 4), 256, 0, stream>>>(Wq, Wk, Wv, Wo, wqkvt, wot);
  k_pos<<<Bb, 1024, 0, stream>>>(doc, pos);
  k_qkv384<<<dim3(256), 512, 0, stream>>>(xb, wqkvt, pos, qd, kd, vtd);
  k_attn<<<dim3(1024), 256, 0, stream>>>(qd, kd, vtd, pos, ctxd);
  k_out256<<<dim3(256), 512, 0, stream>>>(ctxd, wot, bo, outp);
}